// Round 6
// baseline (2530.059 us; speedup 1.0000x reference)
//
#include <hip/hip_runtime.h>
#include <cstdint>
#include <cstddef>

#define Tsz 512
#define TC  32          // steps per chunk
#define NCH 16          // Tsz / TC

typedef _Float16 f16;
typedef _Float16 half8_t __attribute__((ext_vector_type(8)));
typedef _Float16 half4_t __attribute__((ext_vector_type(4)));
typedef float float4_t __attribute__((ext_vector_type(4)));

__device__ __forceinline__ float fast_exp2(float x) {
  float r; asm("v_exp_f32 %0, %1" : "=v"(r) : "v"(x)); return r;
}
__device__ __forceinline__ void pin(half8_t& v) { asm("" : "+v"(v)); }

#define BARRIER_LG asm volatile("s_waitcnt lgkmcnt(0)\n\ts_barrier" ::: "memory")

// P layout (pre-activation, f32, MFMA C-layout): per (tile,slot,t): 256 cols x
// 16 rows; 64B per col. Thread (q) reads/writes float4 rows q*4..q*4+3.
__device__ __forceinline__ size_t poff(int tile, int slot, int t, int j, int q) {
  return (((size_t)((tile * 2 + slot) * TC + t) * 256 + j) << 6) + ((size_t)q << 4);
}

// ---- layers 0,1: rec (h-GEMM from P) + LAGGED pre-GEMM of NEXT layer's P ----
// 16 waves x 16 j-cols (4 waves/SIMD). hf double-buffered in registers: at
// step tl the pre-GEMM uses hf[prev] (= h_{tl-2}) so its 8 MFMAs + P-store
// issue right after the barrier, BEFORE this step's LDS reads return.
// __launch_bounds__(1024,4) is LOAD-BEARING: grid=96 means 1 block/CU, so a
// 128-VGPR cap costs nothing; without it the compiler targets 64 and spills
// the hf double-buffer to scratch (r5: 144 us/dispatch).
__device__ __forceinline__ void rec01_body(
    char* const smem, const int chunk, const int tile,
    const float* __restrict__ Pin, float* __restrict__ Pout,
    const f16* __restrict__ whh_h, const f16* __restrict__ wihn_h,
    const float* __restrict__ bias_n, f16* __restrict__ st)
{
  char* const h_lds = smem;            // 2 x 8192: [32 groups][16 rows][16B]
  const int tid  = threadIdx.x;        // 0..1023
  const int lane = tid & 63;
  const int wave = tid >> 6;           // 0..15
  const int m    = lane & 15;
  const int q    = lane >> 4;
  const int lo   = m * 16;
  const int slot = chunk & 1;
  const int j    = wave * 16 + m;      // this wave's 16 j-cols

  half8_t whh[8], wihn[8];
  const float biasn = bias_n[j];
#pragma unroll
  for (int c = 0; c < 8; ++c) whh[c]  = *(const half8_t*)(whh_h  + j * 256 + c * 32 + q * 8);
#pragma unroll
  for (int c = 0; c < 8; ++c) wihn[c] = *(const half8_t*)(wihn_h + j * 256 + c * 32 + q * 8);
#pragma unroll
  for (int c = 0; c < 8; ++c) { pin(whh[c]); pin(wihn[c]); }

  if (tid < 512) {
    if (chunk == 0)
      *(float4_t*)(h_lds + tid * 16) = float4_t{0.f, 0.f, 0.f, 0.f};
    else
      *(float4_t*)(h_lds + tid * 16) = *(const float4_t*)((const char*)st + tile * 8192 + tid * 16);
  }

  // P prefetch, 2-deep ping-pong (1 x dwordx4 per thread per step)
  float4_t pld[2];
  auto pload = [&](int tl, float4_t* d) {
    const int tn = (tl > TC - 1) ? (TC - 1) : tl;
    d[0] = *(const float4_t*)((const char*)Pin + poff(tile, slot, tn, j, q));
  };
  pload(0, &pld[0]); pload(1, &pld[1]);

  half8_t hf[2][8];                    // register double-buffer of A-fragments
  BARRIER_LG;                          // h image visible

#pragma unroll 2
  for (int tl = 0; tl < TC; ++tl) {
    const int cu = tl & 1, pv = cu ^ 1;
    char* cur = h_lds + cu * 8192;
    char* nxt = h_lds + pv * 8192;

    // 1) issue this step's LDS reads (h_{tl-1} -> hf[cu])
#pragma unroll
    for (int c = 0; c < 8; ++c) hf[cu][c] = *(const half8_t*)(cur + (c * 4 + q) * 256 + lo);

    // 2) consume + refill P prefetch slot
    float4_t a0 = pld[cu];
    pload(tl + 2, &pld[cu]);

    // 3) pre-stream (independent of this step's reads): row tl-2 from hf[pv]
    //    rows TC-2, TC-1 in epilogue; rows -2,-1 were prev chunk's epilogue.
    if (tl >= 2) {
      float4_t b0 = {biasn, biasn, biasn, biasn};
      float4_t b1 = {0.f, 0.f, 0.f, 0.f};
#pragma unroll
      for (int c = 0; c < 4; ++c) {
        b0 = __builtin_amdgcn_mfma_f32_16x16x32_f16(hf[pv][c],     wihn[c],     b0, 0, 0, 0);
        b1 = __builtin_amdgcn_mfma_f32_16x16x32_f16(hf[pv][c + 4], wihn[c + 4], b1, 0, 0, 0);
      }
      *(float4_t*)((char*)Pout + poff(tile, slot, tl - 2, j, q)) = b0 + b1;
    }

    // 4) rec: acc = P(t) + h(t-1) @ Whh^T ; two independent 4-chains
    float4_t a1 = {0.f, 0.f, 0.f, 0.f};
#pragma unroll
    for (int c = 0; c < 4; ++c) {
      a0 = __builtin_amdgcn_mfma_f32_16x16x32_f16(hf[cu][c],     whh[c],     a0, 0, 0, 0);
      a1 = __builtin_amdgcn_mfma_f32_16x16x32_f16(hf[cu][c + 4], whh[c + 4], a1, 0, 0, 0);
    }
    const float4_t acc = a0 + a1;

    // 5) tanh -> h(t) image. C/D layout: col=lane&15, row=q*4+r.
#pragma unroll
    for (int r = 0; r < 4; ++r) {
      const float e  = fast_exp2(acc[r] * 2.8853900817779268f);   // 2*log2(e)*x
      const float hv = 1.0f - 2.0f * __builtin_amdgcn_rcpf(1.0f + e);
      const int b = q * 4 + r;
      *(f16*)(nxt + (j >> 3) * 256 + b * 16 + (j & 7) * 2) = (f16)hv;
    }
    BARRIER_LG;                        // one barrier/step (lgkm only)
  }

  // epilogue 1: pre row TC-2 from hf[1] (= h_{TC-2}, read at iter TC-1)
  {
    float4_t b0 = {biasn, biasn, biasn, biasn};
    float4_t b1 = {0.f, 0.f, 0.f, 0.f};
#pragma unroll
    for (int c = 0; c < 4; ++c) {
      b0 = __builtin_amdgcn_mfma_f32_16x16x32_f16(hf[1][c],     wihn[c],     b0, 0, 0, 0);
      b1 = __builtin_amdgcn_mfma_f32_16x16x32_f16(hf[1][c + 4], wihn[c + 4], b1, 0, 0, 0);
    }
    *(float4_t*)((char*)Pout + poff(tile, slot, TC - 2, j, q)) = b0 + b1;
  }
  // epilogue 2: pre row TC-1 from final h image (buffer 0)
  {
    half8_t hx[8];
#pragma unroll
    for (int c = 0; c < 8; ++c) hx[c] = *(const half8_t*)(h_lds + (c * 4 + q) * 256 + lo);
    float4_t b0 = {biasn, biasn, biasn, biasn};
    float4_t b1 = {0.f, 0.f, 0.f, 0.f};
#pragma unroll
    for (int c = 0; c < 4; ++c) {
      b0 = __builtin_amdgcn_mfma_f32_16x16x32_f16(hx[c],     wihn[c],     b0, 0, 0, 0);
      b1 = __builtin_amdgcn_mfma_f32_16x16x32_f16(hx[c + 4], wihn[c + 4], b1, 0, 0, 0);
    }
    *(float4_t*)((char*)Pout + poff(tile, slot, TC - 1, j, q)) = b0 + b1;
  }
  if (tid < 512)
    *(float4_t*)((char*)st + tile * 8192 + tid * 16) = *(const float4_t*)(h_lds + tid * 16);
}

// ---- layer 2: rec (from P2) + pre0 for chunk k+1 from xh (closes the ring) ----
// pre0 is register-independent (xp); hoisted between the LDS reads and the
// rec MFMAs so it fills the read-latency window.
template<bool REC, bool PRE>
__device__ __forceinline__ void l2_body(
    char* const smem, const int chunk, const int pre_chunk, const int tile,
    const f16* __restrict__ xh, const float* __restrict__ Pin, float* __restrict__ Pout,
    const f16* __restrict__ whh_h, const f16* __restrict__ wih0_h,
    const float* __restrict__ biasc, f16* __restrict__ st)
{
  char* const h_lds = smem;
  const int tid  = threadIdx.x;        // 0..1023
  const int lane = tid & 63;
  const int wave = tid >> 6;           // 0..15
  const int m    = lane & 15;
  const int q    = lane >> 4;
  const int lo   = m * 16;
  const int slot  = chunk & 1;
  const int pslot = pre_chunk & 1;
  const int j    = wave * 16 + m;

  half8_t whh[8], wih0[2];
  float bias0 = 0.f;
  if constexpr (PRE) {
    bias0 = biasc[j];
#pragma unroll
    for (int c = 0; c < 2; ++c) wih0[c] = *(const half8_t*)(wih0_h + j * 64 + c * 32 + q * 8);
    pin(wih0[0]); pin(wih0[1]);
  }
  if constexpr (REC) {
#pragma unroll
    for (int c = 0; c < 8; ++c) whh[c] = *(const half8_t*)(whh_h + j * 256 + c * 32 + q * 8);
#pragma unroll
    for (int c = 0; c < 8; ++c) pin(whh[c]);
  }

  float4_t pld[2];
  auto pload = [&](int tl, float4_t* d) {
    const int tn = (tl > TC - 1) ? (TC - 1) : tl;
    d[0] = *(const float4_t*)((const char*)Pin + poff(tile, slot, tn, j, q));
  };
  half8_t xp[2][2];                    // x already f16: direct A-fragments
  auto xload = [&](int tl, half8_t* d) {
    const int tn = (tl > TC - 1) ? (TC - 1) : tl;
    const f16* base = xh + ((size_t)(tile * 16 + m) * Tsz + (pre_chunk * TC + tn)) * 64 + q * 8;
    d[0] = *(const half8_t*)base;
    d[1] = *(const half8_t*)(base + 32);
  };

  if constexpr (REC) {
    if (tid < 512) {
      if (chunk == 0)
        *(float4_t*)(h_lds + tid * 16) = float4_t{0.f, 0.f, 0.f, 0.f};
      else
        *(float4_t*)(h_lds + tid * 16) = *(const float4_t*)((const char*)st + tile * 8192 + tid * 16);
    }
    pload(0, &pld[0]); pload(1, &pld[1]);
  }
  if constexpr (PRE) { xload(0, xp[0]); xload(1, xp[1]); }
  if constexpr (REC) BARRIER_LG;

#pragma unroll 2
  for (int tl = 0; tl < TC; ++tl) {
    const int cu = tl & 1;
    if constexpr (REC) {
      char* cur = h_lds + cu * 8192;
      char* nxt = h_lds + (cu ^ 1) * 8192;
      half8_t hf[8];
#pragma unroll
      for (int c = 0; c < 8; ++c) hf[c] = *(const half8_t*)(cur + (c * 4 + q) * 256 + lo);
      float4_t a0 = pld[cu];
      pload(tl + 2, &pld[cu]);
      if constexpr (PRE) {             // fill read-latency window with pre0
        float4_t b = {bias0, bias0, bias0, bias0};
        b = __builtin_amdgcn_mfma_f32_16x16x32_f16(xp[cu][0], wih0[0], b, 0, 0, 0);
        b = __builtin_amdgcn_mfma_f32_16x16x32_f16(xp[cu][1], wih0[1], b, 0, 0, 0);
        xload(tl + 2, xp[cu]);
        *(float4_t*)((char*)Pout + poff(tile, pslot, tl, j, q)) = b;
      }
      float4_t a1 = {0.f, 0.f, 0.f, 0.f};
#pragma unroll
      for (int c = 0; c < 4; ++c) {
        a0 = __builtin_amdgcn_mfma_f32_16x16x32_f16(hf[c],     whh[c],     a0, 0, 0, 0);
        a1 = __builtin_amdgcn_mfma_f32_16x16x32_f16(hf[c + 4], whh[c + 4], a1, 0, 0, 0);
      }
      const float4_t acc = a0 + a1;
#pragma unroll
      for (int r = 0; r < 4; ++r) {
        const float e  = fast_exp2(acc[r] * 2.8853900817779268f);
        const float hv = 1.0f - 2.0f * __builtin_amdgcn_rcpf(1.0f + e);
        const int b = q * 4 + r;
        *(f16*)(nxt + (j >> 3) * 256 + b * 16 + (j & 7) * 2) = (f16)hv;
      }
    } else if constexpr (PRE) {        // PRE-only block: no barriers
      float4_t b = {bias0, bias0, bias0, bias0};
      b = __builtin_amdgcn_mfma_f32_16x16x32_f16(xp[cu][0], wih0[0], b, 0, 0, 0);
      b = __builtin_amdgcn_mfma_f32_16x16x32_f16(xp[cu][1], wih0[1], b, 0, 0, 0);
      xload(tl + 2, xp[cu]);
      *(float4_t*)((char*)Pout + poff(tile, pslot, tl, j, q)) = b;
    }
    if constexpr (REC) BARRIER_LG;
  }

  if constexpr (REC) {
    if (tid < 512)
      *(float4_t*)((char*)st + tile * 8192 + tid * 16) = *(const float4_t*)(h_lds + tid * 16);
  }
}

__global__ __launch_bounds__(1024, 4)
void rnn_chunk_kernel(const f16* __restrict__ xh,
                      float* P0, float* P1, float* P2,
                      const f16* __restrict__ whh0h, const f16* __restrict__ whh1h,
                      const f16* __restrict__ whh2h, const f16* __restrict__ wih0h,
                      const f16* __restrict__ wih1h, const f16* __restrict__ wih2h,
                      const float* __restrict__ biasc,
                      f16* st0, f16* st1, f16* st2, int k)
{
  __shared__ __align__(16) char smem[16384];
  const int layer = blockIdx.x >> 5;
  const int tile  = blockIdx.x & 31;
  if (layer == 0) {
    if (k < NCH) rec01_body(smem, k, tile, P0, P1, whh0h, wih1h, biasc + 256, st0);
  } else if (layer == 1) {
    const int c = k - 1;
    if (c >= 0 && c < NCH) rec01_body(smem, c, tile, P1, P2, whh1h, wih2h, biasc + 512, st1);
  } else {
    const int c  = k - 2;
    const int pc = k + 1;                // P0 for chunk k+1 (consumed next dispatch)
    const bool rec = (c >= 0 && c < NCH);
    const bool pre = (pc < NCH);
    if (rec && pre)  l2_body<true,  true >(smem, c, pc, tile, xh, P2, P0, whh2h, wih0h, biasc, st2);
    else if (rec)    l2_body<true,  false>(smem, c, pc, tile, xh, P2, P0, whh2h, wih0h, biasc, st2);
    else if (pre)    l2_body<false, true >(smem, c, pc, tile, xh, P2, P0, whh2h, wih0h, biasc, st2);
  }
}

// bootstrap: P0 for chunk 0 (before the pipeline starts)
__global__ __launch_bounds__(1024, 4)
void pre0_kernel(const f16* __restrict__ xh, float* P0,
                 const f16* __restrict__ wih0h, const float* __restrict__ biasc)
{
  __shared__ __align__(16) char smem[16384];
  l2_body<false, true>(smem, 0, 0, blockIdx.x, xh, nullptr, P0, nullptr, wih0h, biasc, nullptr);
}

// one-time x convert f32->f16 (removes per-step cvt + halves x traffic in l2)
__global__ void prep_x_kernel(const float* __restrict__ x, f16* __restrict__ xh) {
  const size_t i = ((size_t)blockIdx.x * 256 + threadIdx.x) * 8;
  const float4_t v0 = *(const float4_t*)(x + i);
  const float4_t v1 = *(const float4_t*)(x + i + 4);
  half8_t o;
#pragma unroll
  for (int u = 0; u < 4; ++u) { o[u] = (f16)v0[u]; o[u + 4] = (f16)v1[u]; }
  *(half8_t*)(xh + i) = o;
}

// one-time weight convert f32->f16 + bias combine
__global__ void prep_kernel(const float* __restrict__ wih0, const float* __restrict__ whh0,
                            const float* __restrict__ bih0, const float* __restrict__ bhh0,
                            const float* __restrict__ wih1, const float* __restrict__ whh1,
                            const float* __restrict__ bih1, const float* __restrict__ bhh1,
                            const float* __restrict__ wih2, const float* __restrict__ whh2,
                            const float* __restrict__ bih2, const float* __restrict__ bhh2,
                            f16* wih0h, f16* whh0h, f16* wih1h, f16* whh1h,
                            f16* wih2h, f16* whh2h, float* biasc)
{
  const int i = blockIdx.x * 256 + threadIdx.x;
  if      (i < 16384)  wih0h[i]          = (f16)wih0[i];
  else if (i < 81920)  whh0h[i - 16384]  = (f16)whh0[i - 16384];
  else if (i < 147456) wih1h[i - 81920]  = (f16)wih1[i - 81920];
  else if (i < 212992) whh1h[i - 147456] = (f16)whh1[i - 147456];
  else if (i < 278528) wih2h[i - 212992] = (f16)wih2[i - 212992];
  else if (i < 344064) whh2h[i - 278528] = (f16)whh2[i - 278528];
  else if (i < 344320) biasc[i - 344064]       = bih0[i - 344064] + bhh0[i - 344064];
  else if (i < 344576) biasc[256 + i - 344320] = bih1[i - 344320] + bhh1[i - 344320];
  else if (i < 344832) biasc[512 + i - 344576] = bih2[i - 344576] + bhh2[i - 344576];
}

__global__ void fc_kernel(const f16* __restrict__ st2, const float* __restrict__ w_fc,
                          const float* __restrict__ b_fc, float* __restrict__ outp) {
  const int b = blockIdx.x;            // 512
  const int lane = threadIdx.x;        // 64
  const int tile = b >> 4, bl = b & 15;
  const int j = lane * 4;
  const char* hp = (const char*)st2 + tile * 8192 + (j >> 3) * 256 + bl * 16 + (j & 7) * 2;
  const half4_t hv = *(const half4_t*)hp;
  const float4_t w = *(const float4_t*)(w_fc + j);
  float s = (float)hv[0] * w[0] + (float)hv[1] * w[1] + (float)hv[2] * w[2] + (float)hv[3] * w[3];
#pragma unroll
  for (int off = 32; off > 0; off >>= 1) s += __shfl_down(s, off, 64);
  if (lane == 0) outp[b] = s + b_fc[0];
}

extern "C" void kernel_launch(void* const* d_in, const int* in_sizes, int n_in,
                              void* d_out, int out_size, void* d_ws, size_t ws_size,
                              hipStream_t stream) {
  const float* x     = (const float*)d_in[0];
  const float* w_ih0 = (const float*)d_in[1];
  const float* w_hh0 = (const float*)d_in[2];
  const float* b_ih0 = (const float*)d_in[3];
  const float* b_hh0 = (const float*)d_in[4];
  const float* w_ih1 = (const float*)d_in[5];
  const float* w_hh1 = (const float*)d_in[6];
  const float* b_ih1 = (const float*)d_in[7];
  const float* b_hh1 = (const float*)d_in[8];
  const float* w_ih2 = (const float*)d_in[9];
  const float* w_hh2 = (const float*)d_in[10];
  const float* b_ih2 = (const float*)d_in[11];
  const float* b_hh2 = (const float*)d_in[12];
  const float* w_fc  = (const float*)d_in[13];
  const float* b_fc  = (const float*)d_in[14];

  // ws layout (~136 MB; round-3 proved ws_size >= 269,484,032):
  char* ws = (char*)d_ws;
  float* P0   = (float*)(ws);                   // 33,554,432 (32 tiles x 2 slots x 32 t x 16KB)
  float* P1   = (float*)(ws + 33554432);        // 33,554,432
  float* P2   = (float*)(ws + 67108864);        // 33,554,432
  f16* st0    = (f16*)(ws + 100663296);         //    262,144
  f16* st1    = (f16*)(ws + 100925440);         //    262,144
  f16* st2    = (f16*)(ws + 101187584);         //    262,144
  f16* wih0h  = (f16*)(ws + 101449728);         //     32,768
  f16* whh0h  = (f16*)(ws + 101482496);         //    131,072
  f16* wih1h  = (f16*)(ws + 101613568);         //    131,072
  f16* whh1h  = (f16*)(ws + 101744640);         //    131,072
  f16* wih2h  = (f16*)(ws + 101875712);         //    131,072
  f16* whh2h  = (f16*)(ws + 102006784);         //    131,072
  float* biasc = (float*)(ws + 102137856);      //      3,072
  f16* xh     = (f16*)(ws + 102141952);         // 33,554,432 (x as f16)

  prep_x_kernel<<<8192, 256, 0, stream>>>(x, xh);
  prep_kernel<<<1347, 256, 0, stream>>>(w_ih0, w_hh0, b_ih0, b_hh0,
                                        w_ih1, w_hh1, b_ih1, b_hh1,
                                        w_ih2, w_hh2, b_ih2, b_hh2,
                                        wih0h, whh0h, wih1h, whh1h, wih2h, whh2h, biasc);
  pre0_kernel<<<32, 1024, 0, stream>>>(xh, P0, wih0h, biasc);
  // time-skewed pipeline: dispatch k = rec-L0(k) | rec-L1(k-1) | rec-L2(k-2)+pre0(k+1).
  // All cross-layer data (P only) flows across kernel-launch boundaries.
  for (int k = 0; k < NCH + 2; ++k)
    rnn_chunk_kernel<<<96, 1024, 0, stream>>>(xh, P0, P1, P2,
                                              whh0h, whh1h, whh2h,
                                              wih0h, wih1h, wih2h,
                                              biasc, st0, st1, st2, k);
  fc_kernel<<<512, 64, 0, stream>>>(st2, w_fc, b_fc, (float*)d_out);
}

// Round 7
// 1063.106 us; speedup vs baseline: 2.3799x; 2.3799x over previous
//
#include <hip/hip_runtime.h>
#include <cstdint>
#include <cstddef>

#define Tsz 512
#define TC  32          // steps per chunk
#define NCH 16          // Tsz / TC
#define IMG  8448       // h image: 16 batch rows x (512B j + 16B pad)
#define STSZ 8448       // per-tile state = one image

typedef _Float16 f16;
typedef _Float16 half8_t __attribute__((ext_vector_type(8)));
typedef _Float16 half4_t __attribute__((ext_vector_type(4)));
typedef float float4_t __attribute__((ext_vector_type(4)));

__device__ __forceinline__ float fast_exp2(float x) {
  float r; asm("v_exp_f32 %0, %1" : "=v"(r) : "v"(x)); return r;
}
__device__ __forceinline__ void pin(half8_t& v) { asm("" : "+v"(v)); }

#define BARRIER_LG asm volatile("s_waitcnt lgkmcnt(0)\n\ts_barrier" ::: "memory")

// P layout (pre-activation, f32, TRANSPOSED MFMA C-layout): per (tile,slot,t):
// [16 batch][256 j] f32 = 16KB. Thread (m,q,wave) owns float4 at
// b=m, j=wave*16+q*4 .. +3  -> byte (m<<10) + (jb<<2).
__device__ __forceinline__ size_t pbase(int tile, int slot, int t) {
  return ((size_t)((tile * 2 + slot) * TC + t)) << 14;
}

// ---- layers 0,1: rec (h-GEMM from P) + fused pre-GEMM of NEXT layer's P ----
// 16 waves x 16 j-rows (4 waves/SIMD, r2-proven). TRANSPOSED: A=weights
// (lane&15 = j row), B=h (lane&15 = batch col), D=[j][batch]. Thread's 4
// outputs are 4 consecutive j for one batch -> h-image write is ONE
// ds_write_b64 (vs 8 scalar b16 in the row-major form): kills ~650cy/step
// of LDS write-pipe. h image: [b][j] contiguous, row stride 528B (pad).
__device__ __forceinline__ void rec01_body(
    char* const smem, const int chunk, const int tile,
    const float* __restrict__ Pin, float* __restrict__ Pout,
    const f16* __restrict__ whh_h, const f16* __restrict__ wihn_h,
    const float* __restrict__ bias_n, f16* __restrict__ st)
{
  char* const h_lds = smem;            // 2 x IMG
  const int tid  = threadIdx.x;        // 0..1023
  const int lane = tid & 63;
  const int wave = tid >> 6;           // 0..15
  const int m    = lane & 15;          // batch col (B-frag) / j row (A-frag)
  const int q    = lane >> 4;
  const int jb   = wave * 16 + q * 4;  // first of this thread's 4 j-rows
  const int rb   = m * 528 + q * 16;   // B-frag read base (batch m)

  half8_t whh[8], wihn[8];
  const float4_t biasn = *(const float4_t*)(bias_n + jb);
#pragma unroll
  for (int c = 0; c < 8; ++c) whh[c]  = *(const half8_t*)(whh_h  + (wave * 16 + m) * 256 + c * 32 + q * 8);
#pragma unroll
  for (int c = 0; c < 8; ++c) wihn[c] = *(const half8_t*)(wihn_h + (wave * 16 + m) * 256 + c * 32 + q * 8);
#pragma unroll
  for (int c = 0; c < 8; ++c) { pin(whh[c]); pin(wihn[c]); }

  if (tid < 528) {                     // restore/init h(chunk start), 528x16B
    if (chunk == 0)
      *(float4_t*)(h_lds + tid * 16) = float4_t{0.f, 0.f, 0.f, 0.f};
    else
      *(float4_t*)(h_lds + tid * 16) = *(const float4_t*)((const char*)st + tile * STSZ + tid * 16);
  }

  // P prefetch, 2-deep ping-pong (1 x dwordx4 per thread per step)
  const int slot = chunk & 1;
  float4_t pld[2];
  auto pload = [&](int tl, float4_t* d) {
    const int tn = (tl > TC - 1) ? (TC - 1) : tl;
    d[0] = *(const float4_t*)((const char*)Pin + pbase(tile, slot, tn) + (m << 10) + (jb << 2));
  };
  pload(0, &pld[0]); pload(1, &pld[1]);
  BARRIER_LG;                          // h image visible

#pragma unroll 2
  for (int tl = 0; tl < TC; ++tl) {
    char* cur = h_lds + (tl & 1) * IMG;
    char* nxt = h_lds + ((tl + 1) & 1) * IMG;

    // batch A: k = 0..127
    half8_t hf[4];
#pragma unroll
    for (int c = 0; c < 4; ++c) hf[c] = *(const half8_t*)(cur + rb + c * 64);
    float4_t a0 = pld[tl & 1];
#pragma unroll
    for (int c = 0; c < 4; ++c)
      a0 = __builtin_amdgcn_mfma_f32_16x16x32_f16(whh[c], hf[c], a0, 0, 0, 0);
    float4_t b0 = biasn;
    if (tl >= 1) {
#pragma unroll
      for (int c = 0; c < 4; ++c)
        b0 = __builtin_amdgcn_mfma_f32_16x16x32_f16(wihn[c], hf[c], b0, 0, 0, 0);
    }
    // batch B: k = 128..255 (reuse hf regs)
#pragma unroll
    for (int c = 0; c < 4; ++c) hf[c] = *(const half8_t*)(cur + rb + (c + 4) * 64);
    float4_t a1 = {0.f, 0.f, 0.f, 0.f};
#pragma unroll
    for (int c = 0; c < 4; ++c)
      a1 = __builtin_amdgcn_mfma_f32_16x16x32_f16(whh[c + 4], hf[c], a1, 0, 0, 0);
    if (tl >= 1) {
#pragma unroll
      for (int c = 0; c < 4; ++c)
        b0 = __builtin_amdgcn_mfma_f32_16x16x32_f16(wihn[c + 4], hf[c], b0, 0, 0, 0);
      *(float4_t*)((char*)Pout + pbase(tile, slot, tl - 1) + (m << 10) + (jb << 2)) = b0;
    }
    pload(tl + 2, &pld[tl & 1]);       // refill just-consumed slot

    // tanh -> h(t): D[j=jb+r][b=m]; 4 consecutive j = one b64 store
    const float4_t acc = a0 + a1;
    half4_t hv4;
#pragma unroll
    for (int r = 0; r < 4; ++r) {
      const float e  = fast_exp2(acc[r] * 2.8853900817779268f);   // 2*log2(e)*x
      hv4[r] = (f16)(1.0f - 2.0f * __builtin_amdgcn_rcpf(1.0f + e));
    }
    *(half4_t*)(nxt + m * 528 + jb * 2) = hv4;
    BARRIER_LG;                        // one barrier/step (lgkm only)
  }

  // epilogue: pre for row TC-1 from final h image (buffer 0)
  {
    half8_t hf[4];
    float4_t b0 = biasn;
#pragma unroll
    for (int c = 0; c < 4; ++c) hf[c] = *(const half8_t*)(h_lds + rb + c * 64);
#pragma unroll
    for (int c = 0; c < 4; ++c)
      b0 = __builtin_amdgcn_mfma_f32_16x16x32_f16(wihn[c], hf[c], b0, 0, 0, 0);
#pragma unroll
    for (int c = 0; c < 4; ++c) hf[c] = *(const half8_t*)(h_lds + rb + (c + 4) * 64);
#pragma unroll
    for (int c = 0; c < 4; ++c)
      b0 = __builtin_amdgcn_mfma_f32_16x16x32_f16(wihn[c + 4], hf[c], b0, 0, 0, 0);
    *(float4_t*)((char*)Pout + pbase(tile, slot, TC - 1) + (m << 10) + (jb << 2)) = b0;
  }
  if (tid < 528)
    *(float4_t*)((char*)st + tile * STSZ + tid * 16) = *(const float4_t*)(h_lds + tid * 16);
}

// ---- layer 2: rec (from P2) + pre0 for chunk k+1 from xh (closes the ring) ----
template<bool REC, bool PRE>
__device__ __forceinline__ void l2_body(
    char* const smem, const int chunk, const int pre_chunk, const int tile,
    const f16* __restrict__ xh, const float* __restrict__ Pin, float* __restrict__ Pout,
    const f16* __restrict__ whh_h, const f16* __restrict__ wih0_h,
    const float* __restrict__ biasc, f16* __restrict__ st)
{
  char* const h_lds = smem;
  const int tid  = threadIdx.x;        // 0..1023
  const int lane = tid & 63;
  const int wave = tid >> 6;           // 0..15
  const int m    = lane & 15;
  const int q    = lane >> 4;
  const int jb   = wave * 16 + q * 4;
  const int rb   = m * 528 + q * 16;
  const int slot  = chunk & 1;
  const int pslot = pre_chunk & 1;

  half8_t whh[8], wih0[2];
  float4_t bias0 = {0.f, 0.f, 0.f, 0.f};
  if constexpr (PRE) {
    bias0 = *(const float4_t*)(biasc + jb);
#pragma unroll
    for (int c = 0; c < 2; ++c) wih0[c] = *(const half8_t*)(wih0_h + (wave * 16 + m) * 64 + c * 32 + q * 8);
    pin(wih0[0]); pin(wih0[1]);
  }
  if constexpr (REC) {
#pragma unroll
    for (int c = 0; c < 8; ++c) whh[c] = *(const half8_t*)(whh_h + (wave * 16 + m) * 256 + c * 32 + q * 8);
#pragma unroll
    for (int c = 0; c < 8; ++c) pin(whh[c]);
  }

  float4_t pld[2];
  auto pload = [&](int tl, float4_t* d) {
    const int tn = (tl > TC - 1) ? (TC - 1) : tl;
    d[0] = *(const float4_t*)((const char*)Pin + pbase(tile, slot, tn) + (m << 10) + (jb << 2));
  };
  half8_t xp[2][2];                    // x f16, B-fragments (batch=m)
  auto xload = [&](int tl, half8_t* d) {
    const int tn = (tl > TC - 1) ? (TC - 1) : tl;
    const f16* base = xh + ((size_t)(tile * 16 + m) * Tsz + (pre_chunk * TC + tn)) * 64 + q * 8;
    d[0] = *(const half8_t*)base;
    d[1] = *(const half8_t*)(base + 32);
  };

  if constexpr (REC) {
    if (tid < 528) {
      if (chunk == 0)
        *(float4_t*)(h_lds + tid * 16) = float4_t{0.f, 0.f, 0.f, 0.f};
      else
        *(float4_t*)(h_lds + tid * 16) = *(const float4_t*)((const char*)st + tile * STSZ + tid * 16);
    }
    pload(0, &pld[0]); pload(1, &pld[1]);
  }
  if constexpr (PRE) { xload(0, xp[0]); xload(1, xp[1]); }
  if constexpr (REC) BARRIER_LG;

#pragma unroll 2
  for (int tl = 0; tl < TC; ++tl) {
    const int cu = tl & 1;
    if constexpr (REC) {
      char* cur = h_lds + cu * IMG;
      char* nxt = h_lds + (cu ^ 1) * IMG;
      half8_t hf[4];
#pragma unroll
      for (int c = 0; c < 4; ++c) hf[c] = *(const half8_t*)(cur + rb + c * 64);
      float4_t a0 = pld[cu];
#pragma unroll
      for (int c = 0; c < 4; ++c)
        a0 = __builtin_amdgcn_mfma_f32_16x16x32_f16(whh[c], hf[c], a0, 0, 0, 0);
#pragma unroll
      for (int c = 0; c < 4; ++c) hf[c] = *(const half8_t*)(cur + rb + (c + 4) * 64);
      float4_t a1 = {0.f, 0.f, 0.f, 0.f};
#pragma unroll
      for (int c = 0; c < 4; ++c)
        a1 = __builtin_amdgcn_mfma_f32_16x16x32_f16(whh[c + 4], hf[c], a1, 0, 0, 0);
      pload(tl + 2, &pld[cu]);
      const float4_t acc = a0 + a1;
      half4_t hv4;
#pragma unroll
      for (int r = 0; r < 4; ++r) {
        const float e  = fast_exp2(acc[r] * 2.8853900817779268f);
        hv4[r] = (f16)(1.0f - 2.0f * __builtin_amdgcn_rcpf(1.0f + e));
      }
      *(half4_t*)(nxt + m * 528 + jb * 2) = hv4;
    }
    if constexpr (PRE) {               // P0[pre_chunk][tl] = Wih0 x(t) + b0
      float4_t b = bias0;
      b = __builtin_amdgcn_mfma_f32_16x16x32_f16(wih0[0], xp[cu][0], b, 0, 0, 0);
      b = __builtin_amdgcn_mfma_f32_16x16x32_f16(wih0[1], xp[cu][1], b, 0, 0, 0);
      xload(tl + 2, xp[cu]);
      *(float4_t*)((char*)Pout + pbase(tile, pslot, tl) + (m << 10) + (jb << 2)) = b;
    }
    if constexpr (REC) BARRIER_LG;
  }

  if constexpr (REC) {
    if (tid < 528)
      *(float4_t*)((char*)st + tile * STSZ + tid * 16) = *(const float4_t*)(h_lds + tid * 16);
  }
}

__global__ __launch_bounds__(1024)
void rnn_chunk_kernel(const f16* __restrict__ xh,
                      float* P0, float* P1, float* P2,
                      const f16* __restrict__ whh0h, const f16* __restrict__ whh1h,
                      const f16* __restrict__ whh2h, const f16* __restrict__ wih0h,
                      const f16* __restrict__ wih1h, const f16* __restrict__ wih2h,
                      const float* __restrict__ biasc,
                      f16* st0, f16* st1, f16* st2, int k)
{
  __shared__ __align__(16) char smem[2 * IMG];
  const int layer = blockIdx.x >> 5;
  const int tile  = blockIdx.x & 31;
  if (layer == 0) {
    if (k < NCH) rec01_body(smem, k, tile, P0, P1, whh0h, wih1h, biasc + 256, st0);
  } else if (layer == 1) {
    const int c = k - 1;
    if (c >= 0 && c < NCH) rec01_body(smem, c, tile, P1, P2, whh1h, wih2h, biasc + 512, st1);
  } else {
    const int c  = k - 2;
    const int pc = k + 1;                // P0 for chunk k+1 (consumed next dispatch)
    const bool rec = (c >= 0 && c < NCH);
    const bool pre = (pc < NCH);
    if (rec && pre)  l2_body<true,  true >(smem, c, pc, tile, xh, P2, P0, whh2h, wih0h, biasc, st2);
    else if (rec)    l2_body<true,  false>(smem, c, pc, tile, xh, P2, P0, whh2h, wih0h, biasc, st2);
    else if (pre)    l2_body<false, true >(smem, c, pc, tile, xh, P2, P0, whh2h, wih0h, biasc, st2);
  }
}

// bootstrap: P0 for chunk 0 (before the pipeline starts)
__global__ __launch_bounds__(1024)
void pre0_kernel(const f16* __restrict__ xh, float* P0,
                 const f16* __restrict__ wih0h, const float* __restrict__ biasc)
{
  __shared__ __align__(16) char smem[2 * IMG];
  l2_body<false, true>(smem, 0, 0, blockIdx.x, xh, nullptr, P0, nullptr, wih0h, biasc, nullptr);
}

// one-time x convert f32->f16
__global__ void prep_x_kernel(const float* __restrict__ x, f16* __restrict__ xh) {
  const size_t i = ((size_t)blockIdx.x * 256 + threadIdx.x) * 8;
  const float4_t v0 = *(const float4_t*)(x + i);
  const float4_t v1 = *(const float4_t*)(x + i + 4);
  half8_t o;
#pragma unroll
  for (int u = 0; u < 4; ++u) { o[u] = (f16)v0[u]; o[u + 4] = (f16)v1[u]; }
  *(half8_t*)(xh + i) = o;
}

// one-time weight convert f32->f16 + bias combine
__global__ void prep_kernel(const float* __restrict__ wih0, const float* __restrict__ whh0,
                            const float* __restrict__ bih0, const float* __restrict__ bhh0,
                            const float* __restrict__ wih1, const float* __restrict__ whh1,
                            const float* __restrict__ bih1, const float* __restrict__ bhh1,
                            const float* __restrict__ wih2, const float* __restrict__ whh2,
                            const float* __restrict__ bih2, const float* __restrict__ bhh2,
                            f16* wih0h, f16* whh0h, f16* wih1h, f16* whh1h,
                            f16* wih2h, f16* whh2h, float* biasc)
{
  const int i = blockIdx.x * 256 + threadIdx.x;
  if      (i < 16384)  wih0h[i]          = (f16)wih0[i];
  else if (i < 81920)  whh0h[i - 16384]  = (f16)whh0[i - 16384];
  else if (i < 147456) wih1h[i - 81920]  = (f16)wih1[i - 81920];
  else if (i < 212992) whh1h[i - 147456] = (f16)whh1[i - 147456];
  else if (i < 278528) wih2h[i - 212992] = (f16)wih2[i - 212992];
  else if (i < 344064) whh2h[i - 278528] = (f16)whh2[i - 278528];
  else if (i < 344320) biasc[i - 344064]       = bih0[i - 344064] + bhh0[i - 344064];
  else if (i < 344576) biasc[256 + i - 344320] = bih1[i - 344320] + bhh1[i - 344320];
  else if (i < 344832) biasc[512 + i - 344576] = bih2[i - 344576] + bhh2[i - 344576];
}

// h2 final state layout: per tile [16 b][256 j] f16, row stride 528B
__global__ void fc_kernel(const f16* __restrict__ st2, const float* __restrict__ w_fc,
                          const float* __restrict__ b_fc, float* __restrict__ outp) {
  const int b = blockIdx.x;            // 512
  const int lane = threadIdx.x;        // 64
  const int tile = b >> 4, bl = b & 15;
  const int j = lane * 4;
  const half4_t hv = *(const half4_t*)((const char*)st2 + tile * STSZ + bl * 528 + j * 2);
  const float4_t w = *(const float4_t*)(w_fc + j);
  float s = (float)hv[0] * w[0] + (float)hv[1] * w[1] + (float)hv[2] * w[2] + (float)hv[3] * w[3];
#pragma unroll
  for (int off = 32; off > 0; off >>= 1) s += __shfl_down(s, off, 64);
  if (lane == 0) outp[b] = s + b_fc[0];
}

extern "C" void kernel_launch(void* const* d_in, const int* in_sizes, int n_in,
                              void* d_out, int out_size, void* d_ws, size_t ws_size,
                              hipStream_t stream) {
  const float* x     = (const float*)d_in[0];
  const float* w_ih0 = (const float*)d_in[1];
  const float* w_hh0 = (const float*)d_in[2];
  const float* b_ih0 = (const float*)d_in[3];
  const float* b_hh0 = (const float*)d_in[4];
  const float* w_ih1 = (const float*)d_in[5];
  const float* w_hh1 = (const float*)d_in[6];
  const float* b_ih1 = (const float*)d_in[7];
  const float* b_hh1 = (const float*)d_in[8];
  const float* w_ih2 = (const float*)d_in[9];
  const float* w_hh2 = (const float*)d_in[10];
  const float* b_ih2 = (const float*)d_in[11];
  const float* b_hh2 = (const float*)d_in[12];
  const float* w_fc  = (const float*)d_in[13];
  const float* b_fc  = (const float*)d_in[14];

  // ws layout (~137 MB; ws_size >= 269,484,032):
  char* ws = (char*)d_ws;
  float* P0   = (float*)(ws);                   // 33,554,432
  float* P1   = (float*)(ws + 33554432);        // 33,554,432
  float* P2   = (float*)(ws + 67108864);        // 33,554,432
  f16* st0    = (f16*)(ws + 100663296);         //    270,336 (pad to 524,288)
  f16* st1    = (f16*)(ws + 101187584);
  f16* st2    = (f16*)(ws + 101711872);
  f16* wih0h  = (f16*)(ws + 102236160);         //     32,768
  f16* whh0h  = (f16*)(ws + 102268928);         //    131,072
  f16* wih1h  = (f16*)(ws + 102400000);         //    131,072
  f16* whh1h  = (f16*)(ws + 102531072);         //    131,072
  f16* wih2h  = (f16*)(ws + 102662144);         //    131,072
  f16* whh2h  = (f16*)(ws + 102793216);         //    131,072
  float* biasc = (float*)(ws + 102924288);      //      3,072
  f16* xh     = (f16*)(ws + 102928384);         // 33,554,432 (x as f16)

  prep_x_kernel<<<8192, 256, 0, stream>>>(x, xh);
  prep_kernel<<<1347, 256, 0, stream>>>(w_ih0, w_hh0, b_ih0, b_hh0,
                                        w_ih1, w_hh1, b_ih1, b_hh1,
                                        w_ih2, w_hh2, b_ih2, b_hh2,
                                        wih0h, whh0h, wih1h, whh1h, wih2h, whh2h, biasc);
  pre0_kernel<<<32, 1024, 0, stream>>>(xh, P0, wih0h, biasc);
  // time-skewed pipeline: dispatch k = rec-L0(k) | rec-L1(k-1) | rec-L2(k-2)+pre0(k+1).
  for (int k = 0; k < NCH + 2; ++k)
    rnn_chunk_kernel<<<96, 1024, 0, stream>>>(xh, P0, P1, P2,
                                              whh0h, whh1h, whh2h,
                                              wih0h, wih1h, wih2h,
                                              biasc, st0, st1, st2, k);
  fc_kernel<<<512, 64, 0, stream>>>(st2, w_fc, b_fc, (float*)d_out);
}

// Round 8
// 1056.052 us; speedup vs baseline: 2.3958x; 1.0067x over previous
//
#include <hip/hip_runtime.h>
#include <cstdint>
#include <cstddef>

#define Tsz 512
#define TC  32          // steps per chunk
#define NCH 16          // Tsz / TC
#define IMG  8192       // h image: [jchunk=32][batch=16][8 f16] (r2-proven layout)
#define STSZ 8192       // per-tile state = one image

typedef _Float16 f16;
typedef _Float16 half8_t __attribute__((ext_vector_type(8)));
typedef _Float16 half4_t __attribute__((ext_vector_type(4)));
typedef float float4_t __attribute__((ext_vector_type(4)));

__device__ __forceinline__ float fast_exp2(float x) {
  float r; asm("v_exp_f32 %0, %1" : "=v"(r) : "v"(x)); return r;
}
__device__ __forceinline__ void pin(half8_t& v) { asm("" : "+v"(v)); }

#define BARRIER_LG asm volatile("s_waitcnt lgkmcnt(0)\n\ts_barrier" ::: "memory")

// P layout (pre-activation, f32, transposed MFMA C-layout): per (tile,slot,t):
// [16 batch][256 j] f32 = 16KB. Thread (m,q,wave) owns float4 at
// b=m, j=wave*16+q*4 .. +3  -> byte (m<<10) + (jb<<2).
__device__ __forceinline__ size_t pbase(int tile, int slot, int t) {
  return ((size_t)((tile * 2 + slot) * TC + t)) << 14;
}

// ---- layers 0,1: rec (h-GEMM from P) + fused pre-GEMM of NEXT layer's P ----
// 16 waves x 16 j-rows (4 waves/SIMD). TRANSPOSED MFMA: A=weights (lane&15 =
// j row), B=h (lane&15 = batch col), D=[j][batch]. h image keeps r2's EXACT
// byte layout [jchunk][batch][16B]: reads are byte-identical to the proven
// low-conflict pattern; the transposed D writes 4 consecutive j for one batch
// = ONE ds_write_b64 into one cell (vs 8 scalar b16) -> LDS write pipe
// 128 -> 16 instrs/step/CU with no read-pattern change (r7's 528-stride
// [b][j] image was an 8-way bank conflict on reads: 1.8M conflicts).
__device__ __forceinline__ void rec01_body(
    char* const smem, const int chunk, const int tile,
    const float* __restrict__ Pin, float* __restrict__ Pout,
    const f16* __restrict__ whh_h, const f16* __restrict__ wihn_h,
    const float* __restrict__ bias_n, f16* __restrict__ st)
{
  char* const h_lds = smem;            // 2 x IMG
  const int tid  = threadIdx.x;        // 0..1023
  const int lane = tid & 63;
  const int wave = tid >> 6;           // 0..15
  const int m    = lane & 15;          // batch col (B-frag) / j row (A-frag)
  const int q    = lane >> 4;
  const int jb   = wave * 16 + q * 4;  // first of this thread's 4 j-rows
  const int rb   = q * 256 + m * 16;   // B-frag read base: cell (c*4+q, m)
  const int wb   = (wave * 2 + (q >> 1)) * 256 + m * 16 + (q & 1) * 8;  // h write

  half8_t whh[8], wihn[8];
  const float4_t biasn = *(const float4_t*)(bias_n + jb);
#pragma unroll
  for (int c = 0; c < 8; ++c) whh[c]  = *(const half8_t*)(whh_h  + (wave * 16 + m) * 256 + c * 32 + q * 8);
#pragma unroll
  for (int c = 0; c < 8; ++c) wihn[c] = *(const half8_t*)(wihn_h + (wave * 16 + m) * 256 + c * 32 + q * 8);
#pragma unroll
  for (int c = 0; c < 8; ++c) { pin(whh[c]); pin(wihn[c]); }

  if (tid < 512) {                     // restore/init h(chunk start)
    if (chunk == 0)
      *(float4_t*)(h_lds + tid * 16) = float4_t{0.f, 0.f, 0.f, 0.f};
    else
      *(float4_t*)(h_lds + tid * 16) = *(const float4_t*)((const char*)st + tile * STSZ + tid * 16);
  }

  // P prefetch, 2-deep ping-pong (1 x dwordx4 per thread per step)
  const int slot = chunk & 1;
  float4_t pld[2];
  auto pload = [&](int tl, float4_t* d) {
    const int tn = (tl > TC - 1) ? (TC - 1) : tl;
    d[0] = *(const float4_t*)((const char*)Pin + pbase(tile, slot, tn) + (m << 10) + (jb << 2));
  };
  pload(0, &pld[0]); pload(1, &pld[1]);
  BARRIER_LG;                          // h image visible

#pragma unroll 2
  for (int tl = 0; tl < TC; ++tl) {
    char* cur = h_lds + (tl & 1) * IMG;
    char* nxt = h_lds + ((tl + 1) & 1) * IMG;

    // batch A: k = 0..127  (cells (c*4+q, m), byte rb + c*1024)
    half8_t hf[4];
#pragma unroll
    for (int c = 0; c < 4; ++c) hf[c] = *(const half8_t*)(cur + rb + c * 1024);
    float4_t a0 = pld[tl & 1];
#pragma unroll
    for (int c = 0; c < 4; ++c)
      a0 = __builtin_amdgcn_mfma_f32_16x16x32_f16(whh[c], hf[c], a0, 0, 0, 0);
    float4_t b0 = biasn;
    if (tl >= 1) {
#pragma unroll
      for (int c = 0; c < 4; ++c)
        b0 = __builtin_amdgcn_mfma_f32_16x16x32_f16(wihn[c], hf[c], b0, 0, 0, 0);
    }
    // batch B: k = 128..255 (reuse hf regs)
#pragma unroll
    for (int c = 0; c < 4; ++c) hf[c] = *(const half8_t*)(cur + rb + 4096 + c * 1024);
    float4_t a1 = {0.f, 0.f, 0.f, 0.f};
#pragma unroll
    for (int c = 0; c < 4; ++c)
      a1 = __builtin_amdgcn_mfma_f32_16x16x32_f16(whh[c + 4], hf[c], a1, 0, 0, 0);
    if (tl >= 1) {
#pragma unroll
      for (int c = 0; c < 4; ++c)
        b0 = __builtin_amdgcn_mfma_f32_16x16x32_f16(wihn[c + 4], hf[c], b0, 0, 0, 0);
      *(float4_t*)((char*)Pout + pbase(tile, slot, tl - 1) + (m << 10) + (jb << 2)) = b0;
    }
    pload(tl + 2, &pld[tl & 1]);       // refill just-consumed slot

    // tanh -> h(t): D[j=jb+r][b=m] -> one b64 into cell (jb>>3, m)
    const float4_t acc = a0 + a1;
    half4_t hv4;
#pragma unroll
    for (int r = 0; r < 4; ++r) {
      const float e  = fast_exp2(acc[r] * 2.8853900817779268f);   // 2*log2(e)*x
      hv4[r] = (f16)(1.0f - 2.0f * __builtin_amdgcn_rcpf(1.0f + e));
    }
    *(half4_t*)(nxt + wb) = hv4;
    BARRIER_LG;                        // one barrier/step (lgkm only)
  }

  // epilogue: pre for row TC-1 from final h image (buffer 0)
  {
    half8_t hf[4];
    float4_t b0 = biasn;
#pragma unroll
    for (int c = 0; c < 4; ++c) hf[c] = *(const half8_t*)(h_lds + rb + c * 1024);
#pragma unroll
    for (int c = 0; c < 4; ++c)
      b0 = __builtin_amdgcn_mfma_f32_16x16x32_f16(wihn[c], hf[c], b0, 0, 0, 0);
#pragma unroll
    for (int c = 0; c < 4; ++c) hf[c] = *(const half8_t*)(h_lds + rb + 4096 + c * 1024);
#pragma unroll
    for (int c = 0; c < 4; ++c)
      b0 = __builtin_amdgcn_mfma_f32_16x16x32_f16(wihn[c + 4], hf[c], b0, 0, 0, 0);
    *(float4_t*)((char*)Pout + pbase(tile, slot, TC - 1) + (m << 10) + (jb << 2)) = b0;
  }
  if (tid < 512)
    *(float4_t*)((char*)st + tile * STSZ + tid * 16) = *(const float4_t*)(h_lds + tid * 16);
}

// ---- layer 2: rec (from P2) + pre0 for chunk k+1 from xh (closes the ring) ----
template<bool REC, bool PRE>
__device__ __forceinline__ void l2_body(
    char* const smem, const int chunk, const int pre_chunk, const int tile,
    const f16* __restrict__ xh, const float* __restrict__ Pin, float* __restrict__ Pout,
    const f16* __restrict__ whh_h, const f16* __restrict__ wih0_h,
    const float* __restrict__ biasc, f16* __restrict__ st)
{
  char* const h_lds = smem;
  const int tid  = threadIdx.x;        // 0..1023
  const int lane = tid & 63;
  const int wave = tid >> 6;           // 0..15
  const int m    = lane & 15;
  const int q    = lane >> 4;
  const int jb   = wave * 16 + q * 4;
  const int rb   = q * 256 + m * 16;
  const int wb   = (wave * 2 + (q >> 1)) * 256 + m * 16 + (q & 1) * 8;
  const int slot  = chunk & 1;
  const int pslot = pre_chunk & 1;

  half8_t whh[8], wih0[2];
  float4_t bias0 = {0.f, 0.f, 0.f, 0.f};
  if constexpr (PRE) {
    bias0 = *(const float4_t*)(biasc + jb);
#pragma unroll
    for (int c = 0; c < 2; ++c) wih0[c] = *(const half8_t*)(wih0_h + (wave * 16 + m) * 64 + c * 32 + q * 8);
    pin(wih0[0]); pin(wih0[1]);
  }
  if constexpr (REC) {
#pragma unroll
    for (int c = 0; c < 8; ++c) whh[c] = *(const half8_t*)(whh_h + (wave * 16 + m) * 256 + c * 32 + q * 8);
#pragma unroll
    for (int c = 0; c < 8; ++c) pin(whh[c]);
  }

  float4_t pld[2];
  auto pload = [&](int tl, float4_t* d) {
    const int tn = (tl > TC - 1) ? (TC - 1) : tl;
    d[0] = *(const float4_t*)((const char*)Pin + pbase(tile, slot, tn) + (m << 10) + (jb << 2));
  };
  half8_t xp[2][2];                    // x f16, B-fragments (batch=m)
  auto xload = [&](int tl, half8_t* d) {
    const int tn = (tl > TC - 1) ? (TC - 1) : tl;
    const f16* base = xh + ((size_t)(tile * 16 + m) * Tsz + (pre_chunk * TC + tn)) * 64 + q * 8;
    d[0] = *(const half8_t*)base;
    d[1] = *(const half8_t*)(base + 32);
  };

  if constexpr (REC) {
    if (tid < 512) {
      if (chunk == 0)
        *(float4_t*)(h_lds + tid * 16) = float4_t{0.f, 0.f, 0.f, 0.f};
      else
        *(float4_t*)(h_lds + tid * 16) = *(const float4_t*)((const char*)st + tile * STSZ + tid * 16);
    }
    pload(0, &pld[0]); pload(1, &pld[1]);
  }
  if constexpr (PRE) { xload(0, xp[0]); xload(1, xp[1]); }
  if constexpr (REC) BARRIER_LG;

#pragma unroll 2
  for (int tl = 0; tl < TC; ++tl) {
    const int cu = tl & 1;
    if constexpr (REC) {
      char* cur = h_lds + cu * IMG;
      char* nxt = h_lds + (cu ^ 1) * IMG;
      half8_t hf[4];
#pragma unroll
      for (int c = 0; c < 4; ++c) hf[c] = *(const half8_t*)(cur + rb + c * 1024);
      float4_t a0 = pld[cu];
#pragma unroll
      for (int c = 0; c < 4; ++c)
        a0 = __builtin_amdgcn_mfma_f32_16x16x32_f16(whh[c], hf[c], a0, 0, 0, 0);
#pragma unroll
      for (int c = 0; c < 4; ++c) hf[c] = *(const half8_t*)(cur + rb + 4096 + c * 1024);
      float4_t a1 = {0.f, 0.f, 0.f, 0.f};
#pragma unroll
      for (int c = 0; c < 4; ++c)
        a1 = __builtin_amdgcn_mfma_f32_16x16x32_f16(whh[c + 4], hf[c], a1, 0, 0, 0);
      pload(tl + 2, &pld[cu]);
      const float4_t acc = a0 + a1;
      half4_t hv4;
#pragma unroll
      for (int r = 0; r < 4; ++r) {
        const float e  = fast_exp2(acc[r] * 2.8853900817779268f);
        hv4[r] = (f16)(1.0f - 2.0f * __builtin_amdgcn_rcpf(1.0f + e));
      }
      *(half4_t*)(nxt + wb) = hv4;
    }
    if constexpr (PRE) {               // P0[pre_chunk][tl] = Wih0 x(t) + b0
      float4_t b = bias0;
      b = __builtin_amdgcn_mfma_f32_16x16x32_f16(wih0[0], xp[cu][0], b, 0, 0, 0);
      b = __builtin_amdgcn_mfma_f32_16x16x32_f16(wih0[1], xp[cu][1], b, 0, 0, 0);
      xload(tl + 2, xp[cu]);
      *(float4_t*)((char*)Pout + pbase(tile, pslot, tl) + (m << 10) + (jb << 2)) = b;
    }
    if constexpr (REC) BARRIER_LG;
  }

  if constexpr (REC) {
    if (tid < 512)
      *(float4_t*)((char*)st + tile * STSZ + tid * 16) = *(const float4_t*)(h_lds + tid * 16);
  }
}

__global__ __launch_bounds__(1024)
void rnn_chunk_kernel(const f16* __restrict__ xh,
                      float* P0, float* P1, float* P2,
                      const f16* __restrict__ whh0h, const f16* __restrict__ whh1h,
                      const f16* __restrict__ whh2h, const f16* __restrict__ wih0h,
                      const f16* __restrict__ wih1h, const f16* __restrict__ wih2h,
                      const float* __restrict__ biasc,
                      f16* st0, f16* st1, f16* st2, int k)
{
  __shared__ __align__(16) char smem[2 * IMG];
  const int layer = blockIdx.x >> 5;
  const int tile  = blockIdx.x & 31;
  if (layer == 0) {
    if (k < NCH) rec01_body(smem, k, tile, P0, P1, whh0h, wih1h, biasc + 256, st0);
  } else if (layer == 1) {
    const int c = k - 1;
    if (c >= 0 && c < NCH) rec01_body(smem, c, tile, P1, P2, whh1h, wih2h, biasc + 512, st1);
  } else {
    const int c  = k - 2;
    const int pc = k + 1;                // P0 for chunk k+1 (consumed next dispatch)
    const bool rec = (c >= 0 && c < NCH);
    const bool pre = (pc < NCH);
    if (rec && pre)  l2_body<true,  true >(smem, c, pc, tile, xh, P2, P0, whh2h, wih0h, biasc, st2);
    else if (rec)    l2_body<true,  false>(smem, c, pc, tile, xh, P2, P0, whh2h, wih0h, biasc, st2);
    else if (pre)    l2_body<false, true >(smem, c, pc, tile, xh, P2, P0, whh2h, wih0h, biasc, st2);
  }
}

// bootstrap: P0 for chunk 0 (before the pipeline starts)
__global__ __launch_bounds__(1024)
void pre0_kernel(const f16* __restrict__ xh, float* P0,
                 const f16* __restrict__ wih0h, const float* __restrict__ biasc)
{
  __shared__ __align__(16) char smem[2 * IMG];
  l2_body<false, true>(smem, 0, 0, blockIdx.x, xh, nullptr, P0, nullptr, wih0h, biasc, nullptr);
}

// one-time x convert f32->f16
__global__ void prep_x_kernel(const float* __restrict__ x, f16* __restrict__ xh) {
  const size_t i = ((size_t)blockIdx.x * 256 + threadIdx.x) * 8;
  const float4_t v0 = *(const float4_t*)(x + i);
  const float4_t v1 = *(const float4_t*)(x + i + 4);
  half8_t o;
#pragma unroll
  for (int u = 0; u < 4; ++u) { o[u] = (f16)v0[u]; o[u + 4] = (f16)v1[u]; }
  *(half8_t*)(xh + i) = o;
}

// one-time weight convert f32->f16 + bias combine
__global__ void prep_kernel(const float* __restrict__ wih0, const float* __restrict__ whh0,
                            const float* __restrict__ bih0, const float* __restrict__ bhh0,
                            const float* __restrict__ wih1, const float* __restrict__ whh1,
                            const float* __restrict__ bih1, const float* __restrict__ bhh1,
                            const float* __restrict__ wih2, const float* __restrict__ whh2,
                            const float* __restrict__ bih2, const float* __restrict__ bhh2,
                            f16* wih0h, f16* whh0h, f16* wih1h, f16* whh1h,
                            f16* wih2h, f16* whh2h, float* biasc)
{
  const int i = blockIdx.x * 256 + threadIdx.x;
  if      (i < 16384)  wih0h[i]          = (f16)wih0[i];
  else if (i < 81920)  whh0h[i - 16384]  = (f16)whh0[i - 16384];
  else if (i < 147456) wih1h[i - 81920]  = (f16)wih1[i - 81920];
  else if (i < 212992) whh1h[i - 147456] = (f16)whh1[i - 147456];
  else if (i < 278528) wih2h[i - 212992] = (f16)wih2[i - 212992];
  else if (i < 344064) whh2h[i - 278528] = (f16)whh2[i - 278528];
  else if (i < 344320) biasc[i - 344064]       = bih0[i - 344064] + bhh0[i - 344064];
  else if (i < 344576) biasc[256 + i - 344320] = bih1[i - 344320] + bhh1[i - 344320];
  else if (i < 344832) biasc[512 + i - 344576] = bih2[i - 344576] + bhh2[i - 344576];
}

// h2 final state: r2 layout [jchunk][batch][8 f16]
__global__ void fc_kernel(const f16* __restrict__ st2, const float* __restrict__ w_fc,
                          const float* __restrict__ b_fc, float* __restrict__ outp) {
  const int b = blockIdx.x;            // 512
  const int lane = threadIdx.x;        // 64
  const int tile = b >> 4, bl = b & 15;
  const int j = lane * 4;
  const char* hp = (const char*)st2 + tile * STSZ + (j >> 3) * 256 + bl * 16 + (j & 7) * 2;
  const half4_t hv = *(const half4_t*)hp;
  const float4_t w = *(const float4_t*)(w_fc + j);
  float s = (float)hv[0] * w[0] + (float)hv[1] * w[1] + (float)hv[2] * w[2] + (float)hv[3] * w[3];
#pragma unroll
  for (int off = 32; off > 0; off >>= 1) s += __shfl_down(s, off, 64);
  if (lane == 0) outp[b] = s + b_fc[0];
}

extern "C" void kernel_launch(void* const* d_in, const int* in_sizes, int n_in,
                              void* d_out, int out_size, void* d_ws, size_t ws_size,
                              hipStream_t stream) {
  const float* x     = (const float*)d_in[0];
  const float* w_ih0 = (const float*)d_in[1];
  const float* w_hh0 = (const float*)d_in[2];
  const float* b_ih0 = (const float*)d_in[3];
  const float* b_hh0 = (const float*)d_in[4];
  const float* w_ih1 = (const float*)d_in[5];
  const float* w_hh1 = (const float*)d_in[6];
  const float* b_ih1 = (const float*)d_in[7];
  const float* b_hh1 = (const float*)d_in[8];
  const float* w_ih2 = (const float*)d_in[9];
  const float* w_hh2 = (const float*)d_in[10];
  const float* b_ih2 = (const float*)d_in[11];
  const float* b_hh2 = (const float*)d_in[12];
  const float* w_fc  = (const float*)d_in[13];
  const float* b_fc  = (const float*)d_in[14];

  // ws layout (~137 MB; ws_size >= 269,484,032):
  char* ws = (char*)d_ws;
  float* P0   = (float*)(ws);                   // 33,554,432
  float* P1   = (float*)(ws + 33554432);        // 33,554,432
  float* P2   = (float*)(ws + 67108864);        // 33,554,432
  f16* st0    = (f16*)(ws + 100663296);         //    262,144
  f16* st1    = (f16*)(ws + 100925440);         //    262,144
  f16* st2    = (f16*)(ws + 101187584);         //    262,144
  f16* wih0h  = (f16*)(ws + 101449728);         //     32,768
  f16* whh0h  = (f16*)(ws + 101482496);         //    131,072
  f16* wih1h  = (f16*)(ws + 101613568);         //    131,072
  f16* whh1h  = (f16*)(ws + 101744640);         //    131,072
  f16* wih2h  = (f16*)(ws + 101875712);         //    131,072
  f16* whh2h  = (f16*)(ws + 102006784);         //    131,072
  float* biasc = (float*)(ws + 102137856);      //      3,072
  f16* xh     = (f16*)(ws + 102141952);         // 33,554,432 (x as f16)

  prep_x_kernel<<<8192, 256, 0, stream>>>(x, xh);
  prep_kernel<<<1347, 256, 0, stream>>>(w_ih0, w_hh0, b_ih0, b_hh0,
                                        w_ih1, w_hh1, b_ih1, b_hh1,
                                        w_ih2, w_hh2, b_ih2, b_hh2,
                                        wih0h, whh0h, wih1h, whh1h, wih2h, whh2h, biasc);
  pre0_kernel<<<32, 1024, 0, stream>>>(xh, P0, wih0h, biasc);
  // time-skewed pipeline: dispatch k = rec-L0(k) | rec-L1(k-1) | rec-L2(k-2)+pre0(k+1).
  for (int k = 0; k < NCH + 2; ++k)
    rnn_chunk_kernel<<<96, 1024, 0, stream>>>(xh, P0, P1, P2,
                                              whh0h, whh1h, whh2h,
                                              wih0h, wih1h, wih2h,
                                              biasc, st0, st1, st2, k);
  fc_kernel<<<512, 64, 0, stream>>>(st2, w_fc, b_fc, (float*)d_out);
}

// Round 9
// 905.857 us; speedup vs baseline: 2.7930x; 1.1658x over previous
//
#include <hip/hip_runtime.h>
#include <cstdint>
#include <cstddef>

#define Tsz 512
#define TC  32          // steps per chunk
#define NCH 16          // Tsz / TC
#define IMG  8192       // h image: [jchunk=32][batch=16][8 f16] (r2-proven layout)
#define STSZ 8192       // per-tile state = one image

typedef _Float16 f16;
typedef _Float16 half8_t __attribute__((ext_vector_type(8)));
typedef _Float16 half4_t __attribute__((ext_vector_type(4)));
typedef float float4_t __attribute__((ext_vector_type(4)));

__device__ __forceinline__ float fast_exp2(float x) {
  float r; asm("v_exp_f32 %0, %1" : "=v"(r) : "v"(x)); return r;
}
__device__ __forceinline__ void pin(half8_t& v) { asm("" : "+v"(v)); }

#define BARRIER_LG asm volatile("s_waitcnt lgkmcnt(0)\n\ts_barrier" ::: "memory")

// P layout (pre-activation, f32, transposed MFMA C-layout, LANE-LINEAR):
// per (tile,slot,t) 16KB, cell (wave,q,m) at wave*1024 + q*256 + m*16.
// Producer and consumer use the same thread mapping, so a wave's P load and
// store are each ONE contiguous 1KB block (8 full cache lines) -- r8's
// [b][j] form was 16 scattered 64B segments/instr (~+550cy/step request cost).
__device__ __forceinline__ size_t pbase(int tile, int slot, int t) {
  return ((size_t)((tile * 2 + slot) * TC + t)) << 14;
}

// ---- layers 0,1: rec (h-GEMM from P) + fused pre-GEMM of NEXT layer's P ----
// 16 waves x 16 j-rows (4 waves/SIMD). TRANSPOSED MFMA: A=weights (lane&15 =
// j row), B=h (lane&15 = batch col), D=[j][batch]. h image keeps r2's EXACT
// byte layout [jchunk][batch][16B]; h-write is one ds_write_b64 per thread.
__device__ __forceinline__ void rec01_body(
    char* const smem, const int chunk, const int tile,
    const float* __restrict__ Pin, float* __restrict__ Pout,
    const f16* __restrict__ whh_h, const f16* __restrict__ wihn_h,
    const float* __restrict__ bias_n, f16* __restrict__ st)
{
  char* const h_lds = smem;            // 2 x IMG
  const int tid  = threadIdx.x;        // 0..1023
  const int lane = tid & 63;
  const int wave = tid >> 6;           // 0..15
  const int m    = lane & 15;          // batch col (B-frag) / j row (A-frag)
  const int q    = lane >> 4;
  const int jb   = wave * 16 + q * 4;  // first of this thread's 4 j-rows
  const int rb   = q * 256 + m * 16;   // B-frag read base: cell (c*4+q, m)
  const int wb   = (wave * 2 + (q >> 1)) * 256 + m * 16 + (q & 1) * 8;  // h write
  const int pb   = (wave << 10) + (q << 8) + (m << 4);  // lane-linear P cell

  half8_t whh[8], wihn[8];
  const float4_t biasn = *(const float4_t*)(bias_n + jb);
#pragma unroll
  for (int c = 0; c < 8; ++c) whh[c]  = *(const half8_t*)(whh_h  + (wave * 16 + m) * 256 + c * 32 + q * 8);
#pragma unroll
  for (int c = 0; c < 8; ++c) wihn[c] = *(const half8_t*)(wihn_h + (wave * 16 + m) * 256 + c * 32 + q * 8);
#pragma unroll
  for (int c = 0; c < 8; ++c) { pin(whh[c]); pin(wihn[c]); }

  if (tid < 512) {                     // restore/init h(chunk start)
    if (chunk == 0)
      *(float4_t*)(h_lds + tid * 16) = float4_t{0.f, 0.f, 0.f, 0.f};
    else
      *(float4_t*)(h_lds + tid * 16) = *(const float4_t*)((const char*)st + tile * STSZ + tid * 16);
  }

  // P prefetch, 2-deep ping-pong (1 x dwordx4 per thread per step)
  const int slot = chunk & 1;
  float4_t pld[2];
  auto pload = [&](int tl, float4_t* d) {
    const int tn = (tl > TC - 1) ? (TC - 1) : tl;
    d[0] = *(const float4_t*)((const char*)Pin + pbase(tile, slot, tn) + pb);
  };
  pload(0, &pld[0]); pload(1, &pld[1]);
  BARRIER_LG;                          // h image visible

#pragma unroll 2
  for (int tl = 0; tl < TC; ++tl) {
    char* cur = h_lds + (tl & 1) * IMG;
    char* nxt = h_lds + ((tl + 1) & 1) * IMG;

    // batch A: k = 0..127  (cells (c*4+q, m), byte rb + c*1024)
    half8_t hf[4];
#pragma unroll
    for (int c = 0; c < 4; ++c) hf[c] = *(const half8_t*)(cur + rb + c * 1024);
    float4_t a0 = pld[tl & 1];
#pragma unroll
    for (int c = 0; c < 4; ++c)
      a0 = __builtin_amdgcn_mfma_f32_16x16x32_f16(whh[c], hf[c], a0, 0, 0, 0);
    float4_t b0 = biasn;
    if (tl >= 1) {
#pragma unroll
      for (int c = 0; c < 4; ++c)
        b0 = __builtin_amdgcn_mfma_f32_16x16x32_f16(wihn[c], hf[c], b0, 0, 0, 0);
    }
    // batch B: k = 128..255 (reuse hf regs)
#pragma unroll
    for (int c = 0; c < 4; ++c) hf[c] = *(const half8_t*)(cur + rb + 4096 + c * 1024);
    float4_t a1 = {0.f, 0.f, 0.f, 0.f};
#pragma unroll
    for (int c = 0; c < 4; ++c)
      a1 = __builtin_amdgcn_mfma_f32_16x16x32_f16(whh[c + 4], hf[c], a1, 0, 0, 0);
    if (tl >= 1) {
#pragma unroll
      for (int c = 0; c < 4; ++c)
        b0 = __builtin_amdgcn_mfma_f32_16x16x32_f16(wihn[c + 4], hf[c], b0, 0, 0, 0);
      *(float4_t*)((char*)Pout + pbase(tile, slot, tl - 1) + pb) = b0;
    }
    pload(tl + 2, &pld[tl & 1]);       // refill just-consumed slot

    // tanh -> h(t): D[j=jb+r][b=m] -> one b64 into cell (jb>>3, m)
    const float4_t acc = a0 + a1;
    half4_t hv4;
#pragma unroll
    for (int r = 0; r < 4; ++r) {
      const float e  = fast_exp2(acc[r] * 2.8853900817779268f);   // 2*log2(e)*x
      hv4[r] = (f16)(1.0f - 2.0f * __builtin_amdgcn_rcpf(1.0f + e));
    }
    *(half4_t*)(nxt + wb) = hv4;
    BARRIER_LG;                        // one barrier/step (lgkm only)
  }

  // epilogue: pre for row TC-1 from final h image (buffer 0)
  {
    half8_t hf[4];
    float4_t b0 = biasn;
#pragma unroll
    for (int c = 0; c < 4; ++c) hf[c] = *(const half8_t*)(h_lds + rb + c * 1024);
#pragma unroll
    for (int c = 0; c < 4; ++c)
      b0 = __builtin_amdgcn_mfma_f32_16x16x32_f16(wihn[c], hf[c], b0, 0, 0, 0);
#pragma unroll
    for (int c = 0; c < 4; ++c) hf[c] = *(const half8_t*)(h_lds + rb + 4096 + c * 1024);
#pragma unroll
    for (int c = 0; c < 4; ++c)
      b0 = __builtin_amdgcn_mfma_f32_16x16x32_f16(wihn[c + 4], hf[c], b0, 0, 0, 0);
    *(float4_t*)((char*)Pout + pbase(tile, slot, TC - 1) + pb) = b0;
  }
  if (tid < 512)
    *(float4_t*)((char*)st + tile * STSZ + tid * 16) = *(const float4_t*)(h_lds + tid * 16);
}

// ---- layer 2: rec (from P2) + pre0 for chunk k+1 from xh (closes the ring) ----
template<bool REC, bool PRE>
__device__ __forceinline__ void l2_body(
    char* const smem, const int chunk, const int pre_chunk, const int tile,
    const f16* __restrict__ xh, const float* __restrict__ Pin, float* __restrict__ Pout,
    const f16* __restrict__ whh_h, const f16* __restrict__ wih0_h,
    const float* __restrict__ biasc, f16* __restrict__ st)
{
  char* const h_lds = smem;
  const int tid  = threadIdx.x;        // 0..1023
  const int lane = tid & 63;
  const int wave = tid >> 6;           // 0..15
  const int m    = lane & 15;
  const int q    = lane >> 4;
  const int jb   = wave * 16 + q * 4;
  const int rb   = q * 256 + m * 16;
  const int wb   = (wave * 2 + (q >> 1)) * 256 + m * 16 + (q & 1) * 8;
  const int pb   = (wave << 10) + (q << 8) + (m << 4);
  const int slot  = chunk & 1;
  const int pslot = pre_chunk & 1;

  half8_t whh[8], wih0[2];
  float4_t bias0 = {0.f, 0.f, 0.f, 0.f};
  if constexpr (PRE) {
    bias0 = *(const float4_t*)(biasc + jb);
#pragma unroll
    for (int c = 0; c < 2; ++c) wih0[c] = *(const half8_t*)(wih0_h + (wave * 16 + m) * 64 + c * 32 + q * 8);
    pin(wih0[0]); pin(wih0[1]);
  }
  if constexpr (REC) {
#pragma unroll
    for (int c = 0; c < 8; ++c) whh[c] = *(const half8_t*)(whh_h + (wave * 16 + m) * 256 + c * 32 + q * 8);
#pragma unroll
    for (int c = 0; c < 8; ++c) pin(whh[c]);
  }

  float4_t pld[2];
  auto pload = [&](int tl, float4_t* d) {
    const int tn = (tl > TC - 1) ? (TC - 1) : tl;
    d[0] = *(const float4_t*)((const char*)Pin + pbase(tile, slot, tn) + pb);
  };
  half8_t xp[2][2];                    // x f16, B-fragments (batch=m)
  auto xload = [&](int tl, half8_t* d) {
    const int tn = (tl > TC - 1) ? (TC - 1) : tl;
    const f16* base = xh + ((size_t)(tile * 16 + m) * Tsz + (pre_chunk * TC + tn)) * 64 + q * 8;
    d[0] = *(const half8_t*)base;
    d[1] = *(const half8_t*)(base + 32);
  };

  if constexpr (REC) {
    if (tid < 512) {
      if (chunk == 0)
        *(float4_t*)(h_lds + tid * 16) = float4_t{0.f, 0.f, 0.f, 0.f};
      else
        *(float4_t*)(h_lds + tid * 16) = *(const float4_t*)((const char*)st + tile * STSZ + tid * 16);
    }
    pload(0, &pld[0]); pload(1, &pld[1]);
  }
  if constexpr (PRE) { xload(0, xp[0]); xload(1, xp[1]); }
  if constexpr (REC) BARRIER_LG;

#pragma unroll 2
  for (int tl = 0; tl < TC; ++tl) {
    const int cu = tl & 1;
    if constexpr (REC) {
      char* cur = h_lds + cu * IMG;
      char* nxt = h_lds + (cu ^ 1) * IMG;
      half8_t hf[4];
#pragma unroll
      for (int c = 0; c < 4; ++c) hf[c] = *(const half8_t*)(cur + rb + c * 1024);
      float4_t a0 = pld[cu];
#pragma unroll
      for (int c = 0; c < 4; ++c)
        a0 = __builtin_amdgcn_mfma_f32_16x16x32_f16(whh[c], hf[c], a0, 0, 0, 0);
#pragma unroll
      for (int c = 0; c < 4; ++c) hf[c] = *(const half8_t*)(cur + rb + 4096 + c * 1024);
      float4_t a1 = {0.f, 0.f, 0.f, 0.f};
#pragma unroll
      for (int c = 0; c < 4; ++c)
        a1 = __builtin_amdgcn_mfma_f32_16x16x32_f16(whh[c + 4], hf[c], a1, 0, 0, 0);
      pload(tl + 2, &pld[cu]);
      const float4_t acc = a0 + a1;
      half4_t hv4;
#pragma unroll
      for (int r = 0; r < 4; ++r) {
        const float e  = fast_exp2(acc[r] * 2.8853900817779268f);
        hv4[r] = (f16)(1.0f - 2.0f * __builtin_amdgcn_rcpf(1.0f + e));
      }
      *(half4_t*)(nxt + wb) = hv4;
    }
    if constexpr (PRE) {               // P0[pre_chunk][tl] = Wih0 x(t) + b0
      float4_t b = bias0;
      b = __builtin_amdgcn_mfma_f32_16x16x32_f16(wih0[0], xp[cu][0], b, 0, 0, 0);
      b = __builtin_amdgcn_mfma_f32_16x16x32_f16(wih0[1], xp[cu][1], b, 0, 0, 0);
      xload(tl + 2, xp[cu]);
      *(float4_t*)((char*)Pout + pbase(tile, pslot, tl) + pb) = b;
    }
    if constexpr (REC) BARRIER_LG;
  }

  if constexpr (REC) {
    if (tid < 512)
      *(float4_t*)((char*)st + tile * STSZ + tid * 16) = *(const float4_t*)(h_lds + tid * 16);
  }
}

__global__ __launch_bounds__(1024)
void rnn_chunk_kernel(const f16* __restrict__ xh,
                      float* P0, float* P1, float* P2,
                      const f16* __restrict__ whh0h, const f16* __restrict__ whh1h,
                      const f16* __restrict__ whh2h, const f16* __restrict__ wih0h,
                      const f16* __restrict__ wih1h, const f16* __restrict__ wih2h,
                      const float* __restrict__ biasc,
                      f16* st0, f16* st1, f16* st2, int k)
{
  __shared__ __align__(16) char smem[2 * IMG];
  const int layer = blockIdx.x >> 5;
  const int tile  = blockIdx.x & 31;
  if (layer == 0) {
    if (k < NCH) rec01_body(smem, k, tile, P0, P1, whh0h, wih1h, biasc + 256, st0);
  } else if (layer == 1) {
    const int c = k - 1;
    if (c >= 0 && c < NCH) rec01_body(smem, c, tile, P1, P2, whh1h, wih2h, biasc + 512, st1);
  } else {
    const int c  = k - 2;
    const int pc = k + 1;                // P0 for chunk k+1 (consumed next dispatch)
    const bool rec = (c >= 0 && c < NCH);
    const bool pre = (pc < NCH);
    if (rec && pre)  l2_body<true,  true >(smem, c, pc, tile, xh, P2, P0, whh2h, wih0h, biasc, st2);
    else if (rec)    l2_body<true,  false>(smem, c, pc, tile, xh, P2, P0, whh2h, wih0h, biasc, st2);
    else if (pre)    l2_body<false, true >(smem, c, pc, tile, xh, P2, P0, whh2h, wih0h, biasc, st2);
  }
}

// bootstrap: P0 for chunk 0 (before the pipeline starts)
__global__ __launch_bounds__(1024)
void pre0_kernel(const f16* __restrict__ xh, float* P0,
                 const f16* __restrict__ wih0h, const float* __restrict__ biasc)
{
  __shared__ __align__(16) char smem[2 * IMG];
  l2_body<false, true>(smem, 0, 0, blockIdx.x, xh, nullptr, P0, nullptr, wih0h, biasc, nullptr);
}

// one-time x convert f32->f16
__global__ void prep_x_kernel(const float* __restrict__ x, f16* __restrict__ xh) {
  const size_t i = ((size_t)blockIdx.x * 256 + threadIdx.x) * 8;
  const float4_t v0 = *(const float4_t*)(x + i);
  const float4_t v1 = *(const float4_t*)(x + i + 4);
  half8_t o;
#pragma unroll
  for (int u = 0; u < 4; ++u) { o[u] = (f16)v0[u]; o[u + 4] = (f16)v1[u]; }
  *(half8_t*)(xh + i) = o;
}

// one-time weight convert f32->f16 + bias combine
__global__ void prep_kernel(const float* __restrict__ wih0, const float* __restrict__ whh0,
                            const float* __restrict__ bih0, const float* __restrict__ bhh0,
                            const float* __restrict__ wih1, const float* __restrict__ whh1,
                            const float* __restrict__ bih1, const float* __restrict__ bhh1,
                            const float* __restrict__ wih2, const float* __restrict__ whh2,
                            const float* __restrict__ bih2, const float* __restrict__ bhh2,
                            f16* wih0h, f16* whh0h, f16* wih1h, f16* whh1h,
                            f16* wih2h, f16* whh2h, float* biasc)
{
  const int i = blockIdx.x * 256 + threadIdx.x;
  if      (i < 16384)  wih0h[i]          = (f16)wih0[i];
  else if (i < 81920)  whh0h[i - 16384]  = (f16)whh0[i - 16384];
  else if (i < 147456) wih1h[i - 81920]  = (f16)wih1[i - 81920];
  else if (i < 212992) whh1h[i - 147456] = (f16)whh1[i - 147456];
  else if (i < 278528) wih2h[i - 212992] = (f16)wih2[i - 212992];
  else if (i < 344064) whh2h[i - 278528] = (f16)whh2[i - 278528];
  else if (i < 344320) biasc[i - 344064]       = bih0[i - 344064] + bhh0[i - 344064];
  else if (i < 344576) biasc[256 + i - 344320] = bih1[i - 344320] + bhh1[i - 344320];
  else if (i < 344832) biasc[512 + i - 344576] = bih2[i - 344576] + bhh2[i - 344576];
}

// h2 final state: r2 layout [jchunk][batch][8 f16]
__global__ void fc_kernel(const f16* __restrict__ st2, const float* __restrict__ w_fc,
                          const float* __restrict__ b_fc, float* __restrict__ outp) {
  const int b = blockIdx.x;            // 512
  const int lane = threadIdx.x;        // 64
  const int tile = b >> 4, bl = b & 15;
  const int j = lane * 4;
  const char* hp = (const char*)st2 + tile * STSZ + (j >> 3) * 256 + bl * 16 + (j & 7) * 2;
  const half4_t hv = *(const half4_t*)hp;
  const float4_t w = *(const float4_t*)(w_fc + j);
  float s = (float)hv[0] * w[0] + (float)hv[1] * w[1] + (float)hv[2] * w[2] + (float)hv[3] * w[3];
#pragma unroll
  for (int off = 32; off > 0; off >>= 1) s += __shfl_down(s, off, 64);
  if (lane == 0) outp[b] = s + b_fc[0];
}

extern "C" void kernel_launch(void* const* d_in, const int* in_sizes, int n_in,
                              void* d_out, int out_size, void* d_ws, size_t ws_size,
                              hipStream_t stream) {
  const float* x     = (const float*)d_in[0];
  const float* w_ih0 = (const float*)d_in[1];
  const float* w_hh0 = (const float*)d_in[2];
  const float* b_ih0 = (const float*)d_in[3];
  const float* b_hh0 = (const float*)d_in[4];
  const float* w_ih1 = (const float*)d_in[5];
  const float* w_hh1 = (const float*)d_in[6];
  const float* b_ih1 = (const float*)d_in[7];
  const float* b_hh1 = (const float*)d_in[8];
  const float* w_ih2 = (const float*)d_in[9];
  const float* w_hh2 = (const float*)d_in[10];
  const float* b_ih2 = (const float*)d_in[11];
  const float* b_hh2 = (const float*)d_in[12];
  const float* w_fc  = (const float*)d_in[13];
  const float* b_fc  = (const float*)d_in[14];

  // ws layout (~137 MB; ws_size >= 269,484,032):
  char* ws = (char*)d_ws;
  float* P0   = (float*)(ws);                   // 33,554,432
  float* P1   = (float*)(ws + 33554432);        // 33,554,432
  float* P2   = (float*)(ws + 67108864);        // 33,554,432
  f16* st0    = (f16*)(ws + 100663296);         //    262,144
  f16* st1    = (f16*)(ws + 100925440);         //    262,144
  f16* st2    = (f16*)(ws + 101187584);         //    262,144
  f16* wih0h  = (f16*)(ws + 101449728);         //     32,768
  f16* whh0h  = (f16*)(ws + 101482496);         //    131,072
  f16* wih1h  = (f16*)(ws + 101613568);         //    131,072
  f16* whh1h  = (f16*)(ws + 101744640);         //    131,072
  f16* wih2h  = (f16*)(ws + 101875712);         //    131,072
  f16* whh2h  = (f16*)(ws + 102006784);         //    131,072
  float* biasc = (float*)(ws + 102137856);      //      3,072
  f16* xh     = (f16*)(ws + 102141952);         // 33,554,432 (x as f16)

  prep_x_kernel<<<8192, 256, 0, stream>>>(x, xh);
  prep_kernel<<<1347, 256, 0, stream>>>(w_ih0, w_hh0, b_ih0, b_hh0,
                                        w_ih1, w_hh1, b_ih1, b_hh1,
                                        w_ih2, w_hh2, b_ih2, b_hh2,
                                        wih0h, whh0h, wih1h, whh1h, wih2h, whh2h, biasc);
  pre0_kernel<<<32, 1024, 0, stream>>>(xh, P0, wih0h, biasc);
  // time-skewed pipeline: dispatch k = rec-L0(k) | rec-L1(k-1) | rec-L2(k-2)+pre0(k+1).
  for (int k = 0; k < NCH + 2; ++k)
    rnn_chunk_kernel<<<96, 1024, 0, stream>>>(xh, P0, P1, P2,
                                              whh0h, whh1h, whh2h,
                                              wih0h, wih1h, wih2h,
                                              biasc, st0, st1, st2, k);
  fc_kernel<<<512, 64, 0, stream>>>(st2, w_fc, b_fc, (float*)d_out);
}